// Round 5
// baseline (197.220 us; speedup 1.0000x reference)
//
#include <hip/hip_runtime.h>

// Problem constants: B=16384, F=100, NCAT=28, CARD=100, C=5, DTOK=128
// NTOK = 128, D = 128. Output [B,128,128] f32 = 1.074 GB (write-bound).
#define BB    16384
#define FF    100
#define NCATT 28
#define NTOK  128
#define CC    5
#define DD    128
#define NB    128  // b-rows per block (doubled: more weight amortization)
#define NJ    (NB / 4)   // 32 b-iterations per wave
// Block geometry: 256 thr = 32 d4 x 2 tp (token-in-pair) x 4 bi(wave).
// One wave (64 lanes) = d4 0..31 x tp 0..1 for ONE b -> contiguous 1 KB NT store.
// Grid: 64 t-pairs x 128 bchunks = 8192, bchunk-major, bijective XCD swizzle:
// each XCD owns 16 consecutive bchunks (contiguous 128 MB write stream,
// 819 KB L2-resident x_num slab).

typedef float f32x4 __attribute__((ext_vector_type(4)));

__global__ __launch_bounds__(256) void fwe_tok_kernel(
    const float* __restrict__ x_num,    // [B,F]
    const int*   __restrict__ x_cat,    // [B,NCAT]
    const float* __restrict__ fwe_w,    // [F,C]
    const float* __restrict__ fwe_b,    // [F,C]
    const float* __restrict__ prelu_a,  // [1]
    const float* __restrict__ tok_w,    // [F,C,D]
    const float* __restrict__ tok_b,    // [NTOK,D]
    const float* __restrict__ cat_emb,  // [NCAT*CARD, D]
    const int*   __restrict__ cat_off,  // [NCAT]
    float*       __restrict__ out)      // [B,NTOK,D]
{
    // Bijective XCD swizzle (grid % 8 == 0): XCD j gets logical blocks
    // [j*cpx, (j+1)*cpx) -- consecutive bchunks stay on one XCD.
    const int cpx     = gridDim.x >> 3;                       // 1024
    const int logical = (blockIdx.x & 7) * cpx + (blockIdx.x >> 3);

    const int tpair = logical & 63;          // tokens (2*tpair, 2*tpair+1)
    const int bBase = (logical >> 6) * NB;   // bchunk-major

    const int d4 = threadIdx.x & 31;         // float4 index within D
    const int tp = (threadIdx.x >> 5) & 1;   // token within pair
    const int bi = threadIdx.x >> 6;         // wave index: 0..3

    const int t  = tpair * 2 + tp;
    const int b0 = bBase + bi * NJ;          // this wave's first b-row

    const f32x4 tb = *(const f32x4*)&tok_b[t * DD + d4 * 4];

    if (t < NCATT) {   // both tokens of the pair categorical (block-uniform)
        const int off = cat_off[t];
        // phase 1: issue all index loads (wave-uniform addresses)
        int idx[NJ];
        #pragma unroll
        for (int j = 0; j < NJ; ++j)
            idx[j] = x_cat[(b0 + j) * NCATT + t] + off;
        // phase 2: gather + bias + NT store
        #pragma unroll
        for (int j = 0; j < NJ; ++j) {
            const f32x4 e = *(const f32x4*)&cat_emb[(long long)idx[j] * DD + d4 * 4];
            f32x4 r = tb + e;
            __builtin_nontemporal_store(
                r, (f32x4*)&out[((long long)(b0 + j) * NTOK + t) * DD + d4 * 4]);
        }
    } else {           // both tokens numeric (NCAT=28 even -> block-uniform)
        const int f = t - NCATT;
        const float a = prelu_a[0];

        // per-feature scalars + weight slices: 5 float4 = 20 VGPRs, loaded once
        float wf[CC], bf[CC];
        f32x4 w[CC];
        #pragma unroll
        for (int c = 0; c < CC; ++c) {
            wf[c] = fwe_w[f * CC + c];
            bf[c] = fwe_b[f * CC + c];
            w[c]  = *(const f32x4*)&tok_w[(f * CC + c) * DD + d4 * 4];
        }

        // phase 1: issue all x loads (wave-uniform addresses)
        float xv[NJ];
        #pragma unroll
        for (int j = 0; j < NJ; ++j)
            xv[j] = x_num[(b0 + j) * FF + f];

        // phase 2: PReLU + 5-term FMA + NT store (pure compute/store stream)
        #pragma unroll
        for (int j = 0; j < NJ; ++j) {
            f32x4 r = tb;
            #pragma unroll
            for (int c = 0; c < CC; ++c) {
                float h = fmaf(xv[j], wf[c], bf[c]);
                h = (h >= 0.0f) ? h : a * h;
                r += h * w[c];
            }
            __builtin_nontemporal_store(
                r, (f32x4*)&out[((long long)(b0 + j) * NTOK + t) * DD + d4 * 4]);
        }
    }
}

extern "C" void kernel_launch(void* const* d_in, const int* in_sizes, int n_in,
                              void* d_out, int out_size, void* d_ws, size_t ws_size,
                              hipStream_t stream) {
    const float* x_num   = (const float*)d_in[0];
    const int*   x_cat   = (const int*)  d_in[1];
    const float* fwe_w   = (const float*)d_in[2];
    const float* fwe_b   = (const float*)d_in[3];
    const float* prelu_a = (const float*)d_in[4];
    const float* tok_w   = (const float*)d_in[5];
    const float* tok_b   = (const float*)d_in[6];
    const float* cat_emb = (const float*)d_in[7];
    const int*   cat_off = (const int*)  d_in[8];
    float* out = (float*)d_out;

    const int block = 256;
    const int grid  = 64 * (BB / NB);   // 64 t-pairs x 128 bchunks = 8192
    fwe_tok_kernel<<<grid, block, 0, stream>>>(
        x_num, x_cat, fwe_w, fwe_b, prelu_a, tok_w, tok_b, cat_emb, cat_off, out);
}

// Round 6
// 192.965 us; speedup vs baseline: 1.0221x; 1.0221x over previous
//
#include <hip/hip_runtime.h>

// Problem constants: B=16384, F=100, NCAT=28, CARD=100, C=5, DTOK=128
// NTOK = 128, D = 128. Output [B,128,128] f32 = 1.074 GB (write-bound).
#define BB    16384
#define FF    100
#define NCATT 28
#define NTOK  128
#define CC    5
#define DD    128
#define NB    128        // b-rows per block (A/B vs R3's 64; loop kept tight)
#define NJ    (NB / 4)   // 32 b-iterations per wave
// Block geometry: 256 thr = 32 d4 x 2 tp (token-in-pair) x 4 bi(wave).
// One wave (64 lanes) = d4 0..31 x tp 0..1 for ONE b -> contiguous 1 KB NT store.
// Grid: 64 t-pairs x 128 bchunks = 8192, bchunk-major, bijective XCD swizzle.

typedef float f32x4 __attribute__((ext_vector_type(4)));

__global__ __launch_bounds__(256) void fwe_tok_kernel(
    const float* __restrict__ x_num,    // [B,F]
    const int*   __restrict__ x_cat,    // [B,NCAT]
    const float* __restrict__ fwe_w,    // [F,C]
    const float* __restrict__ fwe_b,    // [F,C]
    const float* __restrict__ prelu_a,  // [1]
    const float* __restrict__ tok_w,    // [F,C,D]
    const float* __restrict__ tok_b,    // [NTOK,D]
    const float* __restrict__ cat_emb,  // [NCAT*CARD, D]
    const int*   __restrict__ cat_off,  // [NCAT]
    float*       __restrict__ out)      // [B,NTOK,D]
{
    // Bijective XCD swizzle (grid % 8 == 0): XCD j gets logical blocks
    // [j*cpx, (j+1)*cpx) -- consecutive bchunks stay on one XCD.
    const int cpx     = gridDim.x >> 3;                       // 1024
    const int logical = (blockIdx.x & 7) * cpx + (blockIdx.x >> 3);

    const int tpair = logical & 63;          // tokens (2*tpair, 2*tpair+1)
    const int bBase = (logical >> 6) * NB;   // bchunk-major

    const int d4 = threadIdx.x & 31;         // float4 index within D
    const int tp = (threadIdx.x >> 5) & 1;   // token within pair
    const int bi = threadIdx.x >> 6;         // wave index: 0..3

    const int t  = tpair * 2 + tp;
    const int b0 = bBase + bi * NJ;          // this wave's first b-row

    const f32x4 tb = *(const f32x4*)&tok_b[t * DD + d4 * 4];

    if (t < NCATT) {   // both tokens of the pair categorical (block-uniform)
        const int off = cat_off[t];
        #pragma unroll 4
        for (int j = 0; j < NJ; ++j) {
            const int b   = b0 + j;
            const int idx = x_cat[b * NCATT + t] + off;
            const f32x4 e = *(const f32x4*)&cat_emb[(long long)idx * DD + d4 * 4];
            f32x4 r = tb + e;
            __builtin_nontemporal_store(
                r, (f32x4*)&out[((long long)b * NTOK + t) * DD + d4 * 4]);
        }
    } else {           // both tokens numeric (NCAT=28 even -> block-uniform)
        const int f = t - NCATT;
        const float a = prelu_a[0];

        // per-feature scalars + weight slices: 5 float4 = 20 VGPRs, loaded once
        float wf[CC], bf[CC];
        f32x4 w[CC];
        #pragma unroll
        for (int c = 0; c < CC; ++c) {
            wf[c] = fwe_w[f * CC + c];
            bf[c] = fwe_b[f * CC + c];
            w[c]  = *(const f32x4*)&tok_w[(f * CC + c) * DD + d4 * 4];
        }

        #pragma unroll 4
        for (int j = 0; j < NJ; ++j) {
            const int b = b0 + j;
            const float x = x_num[b * FF + f];
            f32x4 r = tb;
            #pragma unroll
            for (int c = 0; c < CC; ++c) {
                float h = fmaf(x, wf[c], bf[c]);
                h = (h >= 0.0f) ? h : a * h;
                r += h * w[c];
            }
            __builtin_nontemporal_store(
                r, (f32x4*)&out[((long long)b * NTOK + t) * DD + d4 * 4]);
        }
    }
}

extern "C" void kernel_launch(void* const* d_in, const int* in_sizes, int n_in,
                              void* d_out, int out_size, void* d_ws, size_t ws_size,
                              hipStream_t stream) {
    const float* x_num   = (const float*)d_in[0];
    const int*   x_cat   = (const int*)  d_in[1];
    const float* fwe_w   = (const float*)d_in[2];
    const float* fwe_b   = (const float*)d_in[3];
    const float* prelu_a = (const float*)d_in[4];
    const float* tok_w   = (const float*)d_in[5];
    const float* tok_b   = (const float*)d_in[6];
    const float* cat_emb = (const float*)d_in[7];
    const int*   cat_off = (const int*)  d_in[8];
    float* out = (float*)d_out;

    const int block = 256;
    const int grid  = 64 * (BB / NB);   // 64 t-pairs x 128 bchunks = 8192
    fwe_tok_kernel<<<grid, block, 0, stream>>>(
        x_num, x_cat, fwe_w, fwe_b, prelu_a, tok_w, tok_b, cat_emb, cat_off, out);
}

// Round 7
// 192.286 us; speedup vs baseline: 1.0257x; 1.0035x over previous
//
#include <hip/hip_runtime.h>

// Problem constants: B=16384, F=100, NCAT=28, CARD=100, C=5, DTOK=128
// NTOK = 128, D = 128. Output [B,128,128] f32 = 1.074 GB (write-bound).
// FINAL (R3 config): one wave = contiguous 1 KB NT store; bchunk-major grid,
// bijective XCD swizzle -> each XCD owns a contiguous 128 MB write region.
// 189.6 us = ~5.9 TB/s total traffic = ~92% of measured pure-store ceiling.
#define BB    16384
#define FF    100
#define NCATT 28
#define NTOK  128
#define CC    5
#define DD    128
#define NB    64   // b-rows per block (NB=128 tested: -1.8%, reverted)
// Block geometry: 256 thr = 32 d4 x 2 tp (token-in-pair) x 4 bi.
// Grid: 64 t-pairs x 256 bchunks = 16384.

typedef float f32x4 __attribute__((ext_vector_type(4)));

__global__ __launch_bounds__(256) void fwe_tok_kernel(
    const float* __restrict__ x_num,    // [B,F]
    const int*   __restrict__ x_cat,    // [B,NCAT]
    const float* __restrict__ fwe_w,    // [F,C]
    const float* __restrict__ fwe_b,    // [F,C]
    const float* __restrict__ prelu_a,  // [1]
    const float* __restrict__ tok_w,    // [F,C,D]
    const float* __restrict__ tok_b,    // [NTOK,D]
    const float* __restrict__ cat_emb,  // [NCAT*CARD, D]
    const int*   __restrict__ cat_off,  // [NCAT]
    float*       __restrict__ out)      // [B,NTOK,D]
{
    // Bijective XCD swizzle (grid % 8 == 0): XCD j gets logical blocks
    // [j*cpx, (j+1)*cpx) -- consecutive bchunks stay on one XCD.
    const int cpx     = gridDim.x >> 3;                       // 2048
    const int logical = (blockIdx.x & 7) * cpx + (blockIdx.x >> 3);

    const int tpair = logical & 63;          // tokens (2*tpair, 2*tpair+1)
    const int bBase = (logical >> 6) * NB;   // bchunk-major

    const int d4 = threadIdx.x & 31;         // float4 index within D
    const int tp = (threadIdx.x >> 5) & 1;   // token within pair
    const int bi = threadIdx.x >> 6;         // 0..3 batch sub-group

    const int t = tpair * 2 + tp;

    const f32x4 tb = *(const f32x4*)&tok_b[t * DD + d4 * 4];

    if (t < NCATT) {   // tpair <= 13: both tokens categorical (block-uniform)
        const int off = cat_off[t];
        #pragma unroll
        for (int j = 0; j < NB / 4; ++j) {
            const int b   = bBase + bi * (NB / 4) + j;
            const int idx = x_cat[b * NCATT + t] + off;
            const f32x4 e = *(const f32x4*)&cat_emb[(long long)idx * DD + d4 * 4];
            f32x4 r = tb + e;
            __builtin_nontemporal_store(r, (f32x4*)&out[((long long)b * NTOK + t) * DD + d4 * 4]);
        }
    } else {           // both tokens numeric (NCAT=28 even -> block-uniform)
        const int f = t - NCATT;
        const float a = prelu_a[0];

        // Per-feature scalars + weight slices hoisted: 5 float4 = 20 VGPRs.
        float wf[CC], bf[CC];
        f32x4 w[CC];
        #pragma unroll
        for (int c = 0; c < CC; ++c) {
            wf[c] = fwe_w[f * CC + c];
            bf[c] = fwe_b[f * CC + c];
            w[c]  = *(const f32x4*)&tok_w[(f * CC + c) * DD + d4 * 4];
        }

        #pragma unroll
        for (int j = 0; j < NB / 4; ++j) {
            const int b = bBase + bi * (NB / 4) + j;
            const float x = x_num[b * FF + f];
            f32x4 r = tb;
            #pragma unroll
            for (int c = 0; c < CC; ++c) {
                float h = fmaf(x, wf[c], bf[c]);
                h = (h >= 0.0f) ? h : a * h;
                r += h * w[c];
            }
            __builtin_nontemporal_store(r, (f32x4*)&out[((long long)b * NTOK + t) * DD + d4 * 4]);
        }
    }
}

extern "C" void kernel_launch(void* const* d_in, const int* in_sizes, int n_in,
                              void* d_out, int out_size, void* d_ws, size_t ws_size,
                              hipStream_t stream) {
    const float* x_num   = (const float*)d_in[0];
    const int*   x_cat   = (const int*)  d_in[1];
    const float* fwe_w   = (const float*)d_in[2];
    const float* fwe_b   = (const float*)d_in[3];
    const float* prelu_a = (const float*)d_in[4];
    const float* tok_w   = (const float*)d_in[5];
    const float* tok_b   = (const float*)d_in[6];
    const float* cat_emb = (const float*)d_in[7];
    const int*   cat_off = (const int*)  d_in[8];
    float* out = (float*)d_out;

    const int block = 256;
    const int grid  = 64 * (BB / NB);   // 64 t-pairs x 256 bchunks = 16384
    fwe_tok_kernel<<<grid, block, 0, stream>>>(
        x_num, x_cat, fwe_w, fwe_b, prelu_a, tok_w, tok_b, cat_emb, cat_off, out);
}